// Round 17
// baseline (212.531 us; speedup 1.0000x reference)
//
#include <hip/hip_runtime.h>
#include <math.h>

// Wave-synchronous phase boundary: scheduling barrier + compiler memory fence.
// Intra-wave LDS ops complete in order on CDNA (validated rounds 3-5,7,8,11,13,16).
#define WSYNC() do { __builtin_amdgcn_wave_barrier(); asm volatile("" ::: "memory"); } while (0)
#define LFENCE() asm volatile("" ::: "memory")

constexpr int FS = 20;   // padded stride (floats): rows 16B-aligned, worst 2-way banks

typedef float v2f __attribute__((ext_vector_type(2)));
__device__ inline v2f pkfma(v2f a, v2f b, v2f c) {   // -> v_pk_fma_f32 (IEEE per elem)
  return __builtin_elementwise_fma(a, b, c);
}

struct alignas(16) WaveMem {
  float P[16 * FS];      // Pinv -> T1 (=M@X0_var)
  float F[16 * FS];      // Phi
  float W[16 * FS];      // We -> M -> sig_int
  float L1[16 * FS];     // X0_var -> Hom_var
  float L4[16 * FS];     // Q -> ext_s -> Phi@sig_int
  float etr[8], eti[8], lamr[8], lami[8];
  float vx0[16], vu[16], vic[16];
};  // 6720 B/wave; x4 = 26880 B/block -> 6 blocks/CU (161280 <= 163840)

__device__ inline float n2n(float v) {
  if (isnan(v)) return 0.0f;
  if (isinf(v)) return v > 0.f ? 3.402823466e38f : -3.402823466e38f;
  return v;
}

__device__ inline float readlane_f(float v, int l) {
  return __int_as_float(__builtin_amdgcn_readlane(__float_as_int(v), l));
}
template<int CTRL>
__device__ inline float dpp_f(float v) {  // DPP cross-lane on the VALU pipe
  return __int_as_float(__builtin_amdgcn_mov_dpp(__float_as_int(v), CTRL, 0xF, 0xF, true));
}
__device__ inline float bperm_f(int baddr, float v) {  // pull lane (baddr>>2)
  return __int_as_float(__builtin_amdgcn_ds_bpermute(baddr, __float_as_int(v)));
}

__device__ inline void load16(float out[16], const float* p) {
#pragma unroll
  for (int c = 0; c < 4; ++c) {
    float4 v = *(const float4*)(p + 4 * c);
    out[4*c+0] = v.x; out[4*c+1] = v.y; out[4*c+2] = v.z; out[4*c+3] = v.w;
  }
}

// C[i16][j0..j0+3] = sum_k A[i16][k] * (TRB ? B[j][k] : B[k][j]); b128 LDS ops,
// packed-FP32 FMA. Per-element op sequence identical to the scalar form
// (no reassociation): bit-identical results.
template<bool TRB>
__device__ inline void mmv(float* C, const float* A, const float* Bm,
                           int i16, int jg, bool absdiag = false)
{
  const int j0 = jg << 2;
  float aA[16];
  load16(aA, &A[i16 * FS]);
  float acc[4];
  if (TRB) {
#pragma unroll
    for (int cp = 0; cp < 2; ++cp) {   // column pair: two independent dot chains
      float bB0[16], bB1[16];
      load16(bB0, &Bm[(j0 + 2*cp) * FS]);
      load16(bB1, &Bm[(j0 + 2*cp + 1) * FS]);
      v2f s = {0.f, 0.f};
#pragma unroll
      for (int k = 0; k < 16; ++k)
        s = pkfma((v2f){aA[k], aA[k]}, (v2f){bB0[k], bB1[k]}, s);
      acc[2*cp] = s.x; acc[2*cp+1] = s.y;
    }
  } else {
    v2f a01 = {0.f, 0.f}, a23 = {0.f, 0.f};
#pragma unroll
    for (int k = 0; k < 16; ++k) {
      float4 bv = *(const float4*)&Bm[k * FS + j0];
      v2f ad = {aA[k], aA[k]};
      a01 = pkfma(ad, (v2f){bv.x, bv.y}, a01);
      a23 = pkfma(ad, (v2f){bv.z, bv.w}, a23);
    }
    acc[0] = a01.x; acc[1] = a01.y; acc[2] = a23.x; acc[3] = a23.y;
  }
  if (absdiag) {
#pragma unroll
    for (int c = 0; c < 4; ++c) if (i16 == j0 + c) acc[c] = fabsf(acc[c]);
  }
  *(float4*)&C[i16 * FS + j0] = make_float4(acc[0], acc[1], acc[2], acc[3]);
}

__global__ __launch_bounds__(256, 6) void nesde_kernel(
    const float* __restrict__ gX0, const float* __restrict__ gXv,
    const float* __restrict__ gU,  const float* __restrict__ gT,
    const float* __restrict__ gQ,  const float* __restrict__ gLr,
    const float* __restrict__ gLi, const float* __restrict__ gVr,
    const float* __restrict__ gVi, float* __restrict__ gOut0,
    float* __restrict__ gOut1, int B)
{
  __shared__ WaveMem sm[4];
  const int wid  = threadIdx.x >> 6;
  const int lane = threadIdx.x & 63;
  const int b = blockIdx.x * 4 + wid;
  if (b >= B) return;
  WaveMem& S = sm[wid];

  const int r4  = lane >> 2;   // GJ row (0..15)
  const int q   = lane & 3;    // GJ quad (owns cols 8q..8q+7)
  const int i16 = lane & 15;   // matmul row
  const int jg  = lane >> 4;   // matmul col group
  const int j0  = jg << 2;

  const float t = gT[b];

  // ---- early global loads (latency hides under phase A/B/GJ) ----
  const float4 xv = *(const float4*)(gXv + (size_t)b * 256 + lane * 4);
  const float4 qv = *(const float4*)(gQ  + (size_t)b * 256 + lane * 4);
  float4 va = make_float4(0.f,0.f,0.f,0.f), vb = va;
  if (q < 2) {
    const float* src = (q == 0) ? gVr : gVi;
    va = *(const float4*)(src + (size_t)b * 128 + r4 * 8);
    vb = *(const float4*)(src + (size_t)b * 128 + r4 * 8 + 4);
  }
  float x0u = 0.f;
  if (q == 2) x0u = gX0[(size_t)b * 16 + r4];
  if (q == 3) x0u = gU [(size_t)b * 16 + r4];

  // ---- phase A: lam + et = exp(lam*t) (lanes 0..7) ----
  if (lane < 8) {
    float lr = gLr[(size_t)b * 8 + lane];
    float li = gLi[(size_t)b * 8 + lane];
    S.lamr[lane] = lr; S.lami[lane] = li;
    float e = expf(lr * t);
    float sn, cs; sincosf(li * t, &sn, &cs);
    S.etr[lane] = e * cs;
    S.eti[lane] = e * sn;
  }
  WSYNC();  // S0

  // ---- phase B: vcoef (-> registers, fast-math) + phi + staging + aug init ----
  float4 vco;
  {  // vcoef: one (p,q) per lane; feeds variance only (rel err ~1e-6 ok)
    const int p = lane >> 3, qq = lane & 7;
    float la  = -(S.lamr[p] + S.lamr[qq]);
    float th1 = S.lami[p] + S.lami[qq];
    float th2 = S.lami[qq] - S.lami[p];
    float exps = __expf(la * t);
    float s1, c1, s2, c2;
    __sincosf(th1 * t, &s1, &c1);
    __sincosf(th2 * t, &s2, &c2);
    float den1 = la * la + th1 * th1;
    float sg1 = (den1 > 0.f) ? 1.f : ((den1 < 0.f) ? -1.f : 0.f);
    float sc1 = sg1 / fmaxf(den1, 1e-10f);
    float cos1 = sc1 * (exps * (la * c1 + th1 * s1) - la);
    float sin1 = sc1 * (exps * (la * s1 - th1 * c1) + th1);
    float den2 = la * la + th2 * th2;
    float sg2 = (den2 > 0.f) ? 1.f : ((den2 < 0.f) ? -1.f : 0.f);
    float sc2 = sg2 / fmaxf(den2, 1e-10f);
    float cos2 = sc2 * (exps * (la * c2 + th2 * s2) - la);
    float sin2 = sc2 * (exps * (la * s2 - th2 * c2) + th2);
    vco = make_float4(0.5f * (cos1 + cos2), 0.5f * (sin1 + sin2),
                      0.5f * (sin1 - sin2), 0.5f * (cos2 - cos1));
  }
  {
    const int si = lane >> 2, sj = (lane & 3) * 4;
    *(float4*)&S.L1[si * FS + sj] = xv;   // X0_var
    *(float4*)&S.L4[si * FS + sj] = qv;   // Q
  }
  if (q == 2) S.vx0[r4] = x0u;
  if (q == 3) S.vu[r4]  = x0u;

  float myv[8] = { va.x, va.y, va.z, va.w, vb.x, vb.y, vb.z, vb.w };
  float ov[8];
#pragma unroll
  for (int e = 0; e < 8; ++e) ov[e] = __shfl_xor(myv[e], 1);  // q0<->q1: Vr<->Vi
  if (q < 2) {
    float er[8], ei[8];
#pragma unroll
    for (int e = 0; e < 8; ++e) { er[e] = S.etr[e]; ei[e] = S.eti[e]; }
    float vr[8], vi[8], ph[8];
#pragma unroll
    for (int e = 0; e < 8; ++e) {
      vr[e] = (q == 0) ? myv[e] : ov[e];
      vi[e] = (q == 0) ? ov[e]  : myv[e];
    }
    if (q == 0) {
#pragma unroll
      for (int e = 0; e < 8; ++e) ph[e] = vr[e] * er[e] - vi[e] * ei[e];
      *(float4*)&S.F[r4 * FS + 0] = make_float4(ph[0], ph[1], ph[2], ph[3]);
      *(float4*)&S.F[r4 * FS + 4] = make_float4(ph[4], ph[5], ph[6], ph[7]);
    } else {
#pragma unroll
      for (int e = 0; e < 8; ++e) ph[e] = vr[e] * ei[e] + vi[e] * er[e];
      *(float4*)&S.F[r4 * FS + 8]  = make_float4(ph[0], ph[1], ph[2], ph[3]);
      *(float4*)&S.F[r4 * FS + 12] = make_float4(ph[4], ph[5], ph[6], ph[7]);
    }
  }

  // aug: lane (r4,q) owns aug[r4][8q..8q+7]; left = Phi0, right = I
  float a[8];
#pragma unroll
  for (int e = 0; e < 8; ++e) {
    float idv = 0.f;
    if (q == 2) idv = (r4 == e)     ? 1.f : 0.f;
    if (q == 3) idv = (r4 == 8 + e) ? 1.f : 0.f;
    a[e] = (q < 2) ? myv[e] : idv;
  }

  // ---- Gauss-Jordan, f32, partial pivoting, virtual swap.
  //      Bit-identical arithmetic to rounds 3-5/7/8/11/13: same pivot choices,
  //      same single-rounded products. Pivot-row broadcast via 8 INDEPENDENT
  //      ds_bpermute (one pipelined LDS round-trip; replaces the serial
  //      LDS write->read + fences of R13). ----
  unsigned used = 0;
  int myk = 0;
#pragma unroll
  for (int k = 0; k < 16; ++k) {
    const int qk = k >> 3, ek = k & 7;
    float av = a[ek];
    float ck = (qk == 0) ? dpp_f<0x00>(av) : dpp_f<0x55>(av);  // quad bcast (VALU)
    float cand = ((used >> r4) & 1u) ? -1.0f : fabsf(ck);
    float mx = cand;
    mx = fmaxf(mx, dpp_f<0x124>(mx));   // row_ror:4
    mx = fmaxf(mx, dpp_f<0x128>(mx));   // row_ror:8
    mx = fmaxf(mx, dpp_f<0x142>(mx));   // row_bcast15
    mx = fmaxf(mx, dpp_f<0x143>(mx));   // row_bcast31
    float smx = readlane_f(mx, 63);     // global max (SGPR)
    unsigned long long msk = __ballot(cand == smx);
    const int pl4 = (__ffsll((long long)msk) - 1) & 60;  // 4*pivot_row (uniform)
    const bool isp = ((lane & 60) == pl4);
    float pval = readlane_f(av, pl4 | qk);
    float pivinv = 1.0f / pval;         // IEEE f32 divide (overlaps bpermutes)
    const int baddr = (pl4 | q) << 2;   // source lane holding my 8-col slice
    float rr[8];
#pragma unroll
    for (int e = 0; e < 8; ++e) rr[e] = bperm_f(baddr, a[e]);
    const v2f pivd = { pivinv, pivinv };
    const v2f nck  = { -ck, -ck };
#pragma unroll
    for (int e2 = 0; e2 < 4; ++e2) {
      v2f rrp = { rr[2*e2], rr[2*e2+1] };
      v2f sp  = rrp * pivd;             // v_pk_mul_f32, same rounding per elem
      v2f up  = pkfma(nck, sp, (v2f){ a[2*e2], a[2*e2+1] });
      a[2*e2]   = isp ? sp.x : up.x;
      a[2*e2+1] = isp ? sp.y : up.y;
    }
    used |= 1u << (pl4 >> 2);
    if (isp) myk = k;
  }

  // ---- extract Pinv: lane (r4, q>=2) holds inv[myk][8(q-2)..+7] ----
  if (q >= 2) {
    const int base = myk * FS + ((q - 2) << 3);
    *(float4*)&S.P[base]     = make_float4(n2n(a[0]), n2n(a[1]), n2n(a[2]), n2n(a[3]));
    *(float4*)&S.P[base + 4] = make_float4(n2n(a[4]), n2n(a[5]), n2n(a[6]), n2n(a[7]));
  }
  WSYNC();  // S1 — P, F, L1, L4, vx0, vu all visible

  // ---- mean path ----
  if (lane < 32) {   // D1: init_cond (lanes 0-15) and ext_u (16-31)
    const float* src = (lane < 16) ? S.vx0 : S.vu;
    float sv[16], pA[16];
    load16(pA, &S.P[i16 * FS]);
    load16(sv, src);
    float d = 0.f;
#pragma unroll
    for (int k = 0; k < 16; ++k) d = fmaf(pA[k], sv[k], d);
    if (lane < 16) S.vic[i16] = d; else S.vu[i16] = d;
  }
  WSYNC();  // S2
  if (lane < 8) {    // D2: lambda_int folded into vic (precise math: mean path)
    float la = -S.lamr[lane], th = S.lami[lane];
    float exps = expf(la * t);
    float sn, cs; sincosf(th * t, &sn, &cs);
    float denom = la * la + th * th;
    float sgn = (denom > 0.f) ? 1.f : ((denom < 0.f) ? -1.f : 0.f);
    float scale = sgn / fmaxf(denom, 1e-10f);
    float ci = scale * (exps * (la * cs + th * sn) - la);
    float si = scale * (exps * (la * sn - th * cs) + th);
    float e0 = S.vu[2 * lane], e1 = S.vu[2 * lane + 1];
    S.vic[2 * lane]     += ci * e0 - si * e1;
    S.vic[2 * lane + 1] += si * e0 + ci * e1;
  }
  WSYNC();  // S3
  if (lane < 16) {   // D3: out0 = Phi @ (init_cond + lambda_int)
    float fA[16], vv[16];
    load16(fA, &S.F[lane * FS]);
    load16(vv, S.vic);
    float d = 0.f;
#pragma unroll
    for (int k = 0; k < 16; ++k) d = fmaf(fA[k], vv[k], d);
    gOut0[(size_t)b * 16 + lane] = d;
  }
  WSYNC();  // S3b

  // ---- variance path: 7 matmuls, one per phase (no scratch pressure) ----
  mmv<false>(S.W,  S.P, S.L4, i16, jg);        WSYNC();  // V1: We = Pinv @ Q
  mmv<true >(S.L4, S.W, S.P,  i16, jg);        WSYNC();  // V2: ext_s = We @ Pinv^T
  mmv<false>(S.W,  S.F, S.P,  i16, jg);        WSYNC();  // V3: M = Phi @ Pinv
  mmv<false>(S.P,  S.W, S.L1, i16, jg);        WSYNC();  // V4: T1 = M @ X0_var
  mmv<true >(S.L1, S.P, S.W,  i16, jg, true);  WSYNC();  // V5: Hom_var = T1 @ M^T (|diag|)

  {  // sig_int: read ext_s (L4), write W (M is dead now)
    const int p2 = i16 >> 1, aa = i16 & 1;
    const int sA = p2 * 8 + (j0 >> 1);   // source lane of first coef quad
    float4 c0, c1;
    c0.x = __shfl(vco.x, sA);     c0.y = __shfl(vco.y, sA);
    c0.z = __shfl(vco.z, sA);     c0.w = __shfl(vco.w, sA);
    c1.x = __shfl(vco.x, sA + 1); c1.y = __shfl(vco.y, sA + 1);
    c1.z = __shfl(vco.z, sA + 1); c1.w = __shfl(vco.w, sA + 1);
    float4 top = *(const float4*)&S.L4[(2 * p2) * FS + j0];
    float4 bot = *(const float4*)&S.L4[(2 * p2 + 1) * FS + j0];
    float tl[4] = { top.x, top.y, top.z, top.w };
    float bl[4] = { bot.x, bot.y, bot.z, bot.w };
    float r[4];
#pragma unroll
    for (int uu = 0; uu < 4; ++uu) {
      float4 c = (uu < 2) ? c0 : c1;
      const int off = 2 * (uu >> 1);
      float d11 = tl[off], d12 = tl[off + 1];
      float d21 = bl[off], d22 = bl[off + 1];
      const int bb = uu & 1;
      if (aa == 0)
        r[uu] = (bb == 0) ? (c.x * d11 - c.y * d21 - c.z * d12 + c.w * d22)
                          : (c.z * d11 - c.w * d21 + c.x * d12 - c.y * d22);
      else
        r[uu] = (bb == 0) ? (c.y * d11 + c.x * d21 - c.w * d12 - c.z * d22)
                          : (c.w * d11 + c.z * d21 + c.y * d12 + c.x * d22);
    }
    *(float4*)&S.W[i16 * FS + j0] = make_float4(r[0], r[1], r[2], r[3]);
  }
  WSYNC();
  mmv<false>(S.L4, S.F, S.W, i16, jg);         WSYNC();  // V6: PS = Phi @ sig_int

  {  // V7: out1 = Hom_var + PS @ Phi^T  (packed column-pair dot chains)
    float aA[16];
    load16(aA, &S.L4[i16 * FS]);
    float acc[4];
#pragma unroll
    for (int cp = 0; cp < 2; ++cp) {
      float bB0[16], bB1[16];
      load16(bB0, &S.F[(j0 + 2*cp) * FS]);
      load16(bB1, &S.F[(j0 + 2*cp + 1) * FS]);
      v2f s = {0.f, 0.f};
#pragma unroll
      for (int k = 0; k < 16; ++k)
        s = pkfma((v2f){aA[k], aA[k]}, (v2f){bB0[k], bB1[k]}, s);
      acc[2*cp] = s.x; acc[2*cp+1] = s.y;
    }
    float4 hv = *(const float4*)&S.L1[i16 * FS + j0];
    float4 o = make_float4(hv.x + acc[0], hv.y + acc[1], hv.z + acc[2], hv.w + acc[3]);
    *(float4*)&gOut1[(size_t)b * 256 + i16 * 16 + j0] = o;
  }
}

extern "C" void kernel_launch(void* const* d_in, const int* in_sizes, int n_in,
                              void* d_out, int out_size, void* d_ws, size_t ws_size,
                              hipStream_t stream) {
  const float* X0 = (const float*)d_in[0];
  const float* Xv = (const float*)d_in[1];
  const float* U  = (const float*)d_in[2];
  const float* T  = (const float*)d_in[3];
  const float* Q  = (const float*)d_in[4];
  const float* Lr = (const float*)d_in[5];
  const float* Li = (const float*)d_in[6];
  const float* Vr = (const float*)d_in[7];
  const float* Vi = (const float*)d_in[8];
  const int B = in_sizes[3];
  float* out0 = (float*)d_out;
  float* out1 = (float*)d_out + (size_t)B * 16;
  const int blocks = (B + 3) / 4;
  hipLaunchKernelGGL(nesde_kernel, dim3(blocks), dim3(256), 0, stream,
                     X0, Xv, U, T, Q, Lr, Li, Vr, Vi, out0, out1, B);
}

// Round 18
// 174.438 us; speedup vs baseline: 1.2184x; 1.2184x over previous
//
#include <hip/hip_runtime.h>
#include <math.h>

// Wave-synchronous phase boundary: scheduling barrier + compiler memory fence.
// Intra-wave LDS ops complete in order on CDNA (validated rounds 3-5,7,8,11,13,16,17).
#define WSYNC() do { __builtin_amdgcn_wave_barrier(); asm volatile("" ::: "memory"); } while (0)
#define LFENCE() asm volatile("" ::: "memory")

constexpr int FS = 20;   // padded stride (floats): rows 16B-aligned, worst 2-way banks

typedef float v2f __attribute__((ext_vector_type(2)));
__device__ inline v2f pkfma(v2f a, v2f b, v2f c) {   // -> v_pk_fma_f32 (IEEE per elem)
  return __builtin_elementwise_fma(a, b, c);
}

struct alignas(16) WaveMem {
  float P[16 * FS];      // Pinv -> T1 (=M@X0_var)
  float F[16 * FS];      // Phi
  float W[16 * FS];      // GJ pivot-row buf (16 floats) -> We -> M -> sig_int
  float L1[16 * FS];     // X0_var -> Hom_var
  float L4[16 * FS];     // Q -> ext_s -> Phi@sig_int
  float etr[8], eti[8], lamr[8], lami[8];
  float vx0[16], vu[16], vic[16];
};  // 6720 B/wave; x4 = 26880 B/block -> 6 blocks/CU (161280 <= 163840)

__device__ inline float n2n(float v) {
  if (isnan(v)) return 0.0f;
  if (isinf(v)) return v > 0.f ? 3.402823466e38f : -3.402823466e38f;
  return v;
}

__device__ inline float readlane_f(float v, int l) {
  return __int_as_float(__builtin_amdgcn_readlane(__float_as_int(v), l));
}
template<int CTRL>
__device__ inline float dpp_f(float v) {  // DPP cross-lane on the VALU pipe
  return __int_as_float(__builtin_amdgcn_mov_dpp(__float_as_int(v), CTRL, 0xF, 0xF, true));
}

__device__ inline void load16(float out[16], const float* p) {
#pragma unroll
  for (int c = 0; c < 4; ++c) {
    float4 v = *(const float4*)(p + 4 * c);
    out[4*c+0] = v.x; out[4*c+1] = v.y; out[4*c+2] = v.z; out[4*c+3] = v.w;
  }
}

// C[i16][j0..j0+3] = sum_k A[i16][k] * (TRB ? B[j][k] : B[k][j]); b128 LDS ops,
// packed-FP32 FMA. Per-element op sequence identical to the scalar form
// (no reassociation): bit-identical results.
template<bool TRB>
__device__ inline void mmv(float* C, const float* A, const float* Bm,
                           int i16, int jg, bool absdiag = false)
{
  const int j0 = jg << 2;
  float aA[16];
  load16(aA, &A[i16 * FS]);
  float acc[4];
  if (TRB) {
#pragma unroll
    for (int cp = 0; cp < 2; ++cp) {   // column pair: two independent dot chains
      float bB0[16], bB1[16];
      load16(bB0, &Bm[(j0 + 2*cp) * FS]);
      load16(bB1, &Bm[(j0 + 2*cp + 1) * FS]);
      v2f s = {0.f, 0.f};
#pragma unroll
      for (int k = 0; k < 16; ++k)
        s = pkfma((v2f){aA[k], aA[k]}, (v2f){bB0[k], bB1[k]}, s);
      acc[2*cp] = s.x; acc[2*cp+1] = s.y;
    }
  } else {
    v2f a01 = {0.f, 0.f}, a23 = {0.f, 0.f};
#pragma unroll
    for (int k = 0; k < 16; ++k) {
      float4 bv = *(const float4*)&Bm[k * FS + j0];
      v2f ad = {aA[k], aA[k]};
      a01 = pkfma(ad, (v2f){bv.x, bv.y}, a01);
      a23 = pkfma(ad, (v2f){bv.z, bv.w}, a23);
    }
    acc[0] = a01.x; acc[1] = a01.y; acc[2] = a23.x; acc[3] = a23.y;
  }
  if (absdiag) {
#pragma unroll
    for (int c = 0; c < 4; ++c) if (i16 == j0 + c) acc[c] = fabsf(acc[c]);
  }
  *(float4*)&C[i16 * FS + j0] = make_float4(acc[0], acc[1], acc[2], acc[3]);
}

__global__ __launch_bounds__(256, 6) void nesde_kernel(
    const float* __restrict__ gX0, const float* __restrict__ gXv,
    const float* __restrict__ gU,  const float* __restrict__ gT,
    const float* __restrict__ gQ,  const float* __restrict__ gLr,
    const float* __restrict__ gLi, const float* __restrict__ gVr,
    const float* __restrict__ gVi, float* __restrict__ gOut0,
    float* __restrict__ gOut1, int B)
{
  __shared__ WaveMem sm[4];
  const int wid  = threadIdx.x >> 6;
  const int lane = threadIdx.x & 63;
  const int b = blockIdx.x * 4 + wid;
  if (b >= B) return;
  WaveMem& S = sm[wid];

  const int r4  = lane >> 2;   // GJ row (0..15)
  const int q   = lane & 3;    // GJ quad (owns cols 4q..4q+3)
  const int i16 = lane & 15;   // matmul row
  const int jg  = lane >> 4;   // matmul col group
  const int j0  = jg << 2;

  const float t = gT[b];

  // ---- early global loads (latency hides under phase A/B/GJ) ----
  const float4 xv = *(const float4*)(gXv + (size_t)b * 256 + lane * 4);
  const float4 qv = *(const float4*)(gQ  + (size_t)b * 256 + lane * 4);
  float4 v4;
  {  // Phi0 slice: cols 4q..4q+3 of row r4 (q0/q1 = Vr, q2/q3 = Vi)
    const float* src = (q < 2) ? gVr : gVi;
    v4 = *(const float4*)(src + (size_t)b * 128 + r4 * 8 + ((q & 1) << 2));
  }
  float x0u = 0.f;
  if (q == 2) x0u = gX0[(size_t)b * 16 + r4];
  if (q == 3) x0u = gU [(size_t)b * 16 + r4];

  // ---- phase A: lam + et = exp(lam*t) (lanes 0..7) ----
  if (lane < 8) {
    float lr = gLr[(size_t)b * 8 + lane];
    float li = gLi[(size_t)b * 8 + lane];
    S.lamr[lane] = lr; S.lami[lane] = li;
    float e = expf(lr * t);
    float sn, cs; sincosf(li * t, &sn, &cs);
    S.etr[lane] = e * cs;
    S.eti[lane] = e * sn;
  }
  WSYNC();  // S0

  // ---- phase B: vcoef (-> registers, fast-math) + phi + staging ----
  float4 vco;
  {  // vcoef: one (p,q) per lane; feeds variance only (rel err ~1e-6 ok)
    const int p = lane >> 3, qq = lane & 7;
    float la  = -(S.lamr[p] + S.lamr[qq]);
    float th1 = S.lami[p] + S.lami[qq];
    float th2 = S.lami[qq] - S.lami[p];
    float exps = __expf(la * t);
    float s1, c1, s2, c2;
    __sincosf(th1 * t, &s1, &c1);
    __sincosf(th2 * t, &s2, &c2);
    float den1 = la * la + th1 * th1;
    float sg1 = (den1 > 0.f) ? 1.f : ((den1 < 0.f) ? -1.f : 0.f);
    float sc1 = sg1 / fmaxf(den1, 1e-10f);
    float cos1 = sc1 * (exps * (la * c1 + th1 * s1) - la);
    float sin1 = sc1 * (exps * (la * s1 - th1 * c1) + th1);
    float den2 = la * la + th2 * th2;
    float sg2 = (den2 > 0.f) ? 1.f : ((den2 < 0.f) ? -1.f : 0.f);
    float sc2 = sg2 / fmaxf(den2, 1e-10f);
    float cos2 = sc2 * (exps * (la * c2 + th2 * s2) - la);
    float sin2 = sc2 * (exps * (la * s2 - th2 * c2) + th2);
    vco = make_float4(0.5f * (cos1 + cos2), 0.5f * (sin1 + sin2),
                      0.5f * (sin1 - sin2), 0.5f * (cos2 - cos1));
  }
  {
    const int si = lane >> 2, sj = (lane & 3) * 4;
    *(float4*)&S.L1[si * FS + sj] = xv;   // X0_var
    *(float4*)&S.L4[si * FS + sj] = qv;   // Q
  }
  if (q == 2) S.vx0[r4] = x0u;
  if (q == 3) S.vu[r4]  = x0u;

  float mv[4] = { v4.x, v4.y, v4.z, v4.w };
  float pvv[4];
#pragma unroll
  for (int e = 0; e < 4; ++e) pvv[e] = __shfl_xor(mv[e], 2);  // q0<->q2, q1<->q3
  {  // phi: Re cols (q<2) = Vr*er - Vi*ei; Im cols (q>=2) = Vr*ei + Vi*er
    const int cbase = (q & 1) << 2;
    float er[4], ei[4], ph[4];
#pragma unroll
    for (int e = 0; e < 4; ++e) { er[e] = S.etr[cbase + e]; ei[e] = S.eti[cbase + e]; }
    if (q < 2) {
#pragma unroll
      for (int e = 0; e < 4; ++e) ph[e] = mv[e] * er[e] - pvv[e] * ei[e];
    } else {
#pragma unroll
      for (int e = 0; e < 4; ++e) ph[e] = pvv[e] * ei[e] + mv[e] * er[e];
    }
    *(float4*)&S.F[r4 * FS + (q << 2)] = make_float4(ph[0], ph[1], ph[2], ph[3]);
  }

  // ---- in-place Gauss-Jordan inversion, f32, partial pivoting, virtual swap.
  //      B starts as Phi0; vacated column k stores inverse column p_k.
  //      Every produced VALUE is bit-identical to the augmented version
  //      (rounds 3-17): same pivot choices, same single-rounded products;
  //      only positions permute (undone at extraction via nibble record). ----
  float a[4] = { mv[0], mv[1], mv[2], mv[3] };
  unsigned used = 0, plo = 0, phh = 0;
  int myk = 0;
#pragma unroll
  for (int k = 0; k < 16; ++k) {
    const int kq = k >> 2, ke = k & 3;
    float av = a[ke];
    float ck = (kq == 0) ? dpp_f<0x00>(av) : (kq == 1) ? dpp_f<0x55>(av)
             : (kq == 2) ? dpp_f<0xAA>(av) : dpp_f<0xFF>(av);  // quad bcast
    float cand = ((used >> r4) & 1u) ? -1.0f : fabsf(ck);
    float mx = cand;
    mx = fmaxf(mx, dpp_f<0x124>(mx));   // row_ror:4
    mx = fmaxf(mx, dpp_f<0x128>(mx));   // row_ror:8
    mx = fmaxf(mx, dpp_f<0x142>(mx));   // row_bcast15
    mx = fmaxf(mx, dpp_f<0x143>(mx));   // row_bcast31
    float smx = readlane_f(mx, 63);     // global max (SGPR)
    unsigned long long msk = __ballot(cand == smx);
    const int pl4 = (__ffsll((long long)msk) - 1) & 60;  // 4*pivot_row (uniform)
    const bool isp = ((lane & 60) == pl4);
    if (isp) *(float4*)&S.W[q << 2] = make_float4(a[0], a[1], a[2], a[3]);
    float pval = readlane_f(av, pl4 | kq);
    float pivinv = 1.0f / pval;         // IEEE f32 divide
    LFENCE();
    float4 rr4 = *(const float4*)&S.W[q << 2];
    LFENCE();
    const v2f pivd = { pivinv, pivinv };
    const v2f nck  = { -ck, -ck };
    {
      v2f sp = (v2f){ rr4.x, rr4.y } * pivd;           // v_pk_mul_f32
      v2f up = pkfma(nck, sp, (v2f){ a[0], a[1] });
      a[0] = isp ? sp.x : up.x;
      a[1] = isp ? sp.y : up.y;
      v2f sp2 = (v2f){ rr4.z, rr4.w } * pivd;
      v2f up2 = pkfma(nck, sp2, (v2f){ a[2], a[3] });
      a[2] = isp ? sp2.x : up2.x;
      a[3] = isp ? sp2.y : up2.y;
    }
    // vacated column k: pivot row gets pivinv; others -(ck*pivinv)
    if (q == kq) a[ke] = isp ? pivinv : -(ck * pivinv);
    used |= 1u << (pl4 >> 2);
    if (isp) myk = k;
    const unsigned p = (unsigned)(pl4 >> 2);
    if (k < 8) plo |= p << (4 * k); else phh |= p << (4 * (k - 8));
  }

  // ---- extraction: physical col c holds inverse col p_c; row r4 -> out row myk ----
  {
#pragma unroll
    for (int e = 0; e < 4; ++e) {
      const int c = (q << 2) + e;
      const unsigned nib = (q < 2) ? (plo >> (4 * c)) : (phh >> (4 * (c - 8)));
      S.P[myk * FS + (nib & 15u)] = n2n(a[e]);
    }
  }
  WSYNC();  // S1 — P, F, L1, L4, vx0, vu all visible

  // ---- mean path ----
  if (lane < 32) {   // D1: init_cond (lanes 0-15) and ext_u (16-31)
    const float* src = (lane < 16) ? S.vx0 : S.vu;
    float sv[16], pA[16];
    load16(pA, &S.P[i16 * FS]);
    load16(sv, src);
    float d = 0.f;
#pragma unroll
    for (int k = 0; k < 16; ++k) d = fmaf(pA[k], sv[k], d);
    if (lane < 16) S.vic[i16] = d; else S.vu[i16] = d;
  }
  WSYNC();  // S2
  if (lane < 8) {    // D2: lambda_int folded into vic (precise math: mean path)
    float la = -S.lamr[lane], th = S.lami[lane];
    float exps = expf(la * t);
    float sn, cs; sincosf(th * t, &sn, &cs);
    float denom = la * la + th * th;
    float sgn = (denom > 0.f) ? 1.f : ((denom < 0.f) ? -1.f : 0.f);
    float scale = sgn / fmaxf(denom, 1e-10f);
    float ci = scale * (exps * (la * cs + th * sn) - la);
    float si = scale * (exps * (la * sn - th * cs) + th);
    float e0 = S.vu[2 * lane], e1 = S.vu[2 * lane + 1];
    S.vic[2 * lane]     += ci * e0 - si * e1;
    S.vic[2 * lane + 1] += si * e0 + ci * e1;
  }
  WSYNC();  // S3
  if (lane < 16) {   // D3: out0 = Phi @ (init_cond + lambda_int)
    float fA[16], vv[16];
    load16(fA, &S.F[lane * FS]);
    load16(vv, S.vic);
    float d = 0.f;
#pragma unroll
    for (int k = 0; k < 16; ++k) d = fmaf(fA[k], vv[k], d);
    gOut0[(size_t)b * 16 + lane] = d;
  }
  WSYNC();  // S3b

  // ---- variance path: 7 matmuls, one per phase (no scratch pressure) ----
  mmv<false>(S.W,  S.P, S.L4, i16, jg);        WSYNC();  // V1: We = Pinv @ Q
  mmv<true >(S.L4, S.W, S.P,  i16, jg);        WSYNC();  // V2: ext_s = We @ Pinv^T
  mmv<false>(S.W,  S.F, S.P,  i16, jg);        WSYNC();  // V3: M = Phi @ Pinv
  mmv<false>(S.P,  S.W, S.L1, i16, jg);        WSYNC();  // V4: T1 = M @ X0_var
  mmv<true >(S.L1, S.P, S.W,  i16, jg, true);  WSYNC();  // V5: Hom_var = T1 @ M^T (|diag|)

  {  // sig_int: read ext_s (L4), write W (M is dead now)
    const int p2 = i16 >> 1, aa = i16 & 1;
    const int sA = p2 * 8 + (j0 >> 1);   // source lane of first coef quad
    float4 c0, c1;
    c0.x = __shfl(vco.x, sA);     c0.y = __shfl(vco.y, sA);
    c0.z = __shfl(vco.z, sA);     c0.w = __shfl(vco.w, sA);
    c1.x = __shfl(vco.x, sA + 1); c1.y = __shfl(vco.y, sA + 1);
    c1.z = __shfl(vco.z, sA + 1); c1.w = __shfl(vco.w, sA + 1);
    float4 top = *(const float4*)&S.L4[(2 * p2) * FS + j0];
    float4 bot = *(const float4*)&S.L4[(2 * p2 + 1) * FS + j0];
    float tl[4] = { top.x, top.y, top.z, top.w };
    float bl[4] = { bot.x, bot.y, bot.z, bot.w };
    float r[4];
#pragma unroll
    for (int uu = 0; uu < 4; ++uu) {
      float4 c = (uu < 2) ? c0 : c1;
      const int off = 2 * (uu >> 1);
      float d11 = tl[off], d12 = tl[off + 1];
      float d21 = bl[off], d22 = bl[off + 1];
      const int bb = uu & 1;
      if (aa == 0)
        r[uu] = (bb == 0) ? (c.x * d11 - c.y * d21 - c.z * d12 + c.w * d22)
                          : (c.z * d11 - c.w * d21 + c.x * d12 - c.y * d22);
      else
        r[uu] = (bb == 0) ? (c.y * d11 + c.x * d21 - c.w * d12 - c.z * d22)
                          : (c.w * d11 + c.z * d21 + c.y * d12 + c.x * d22);
    }
    *(float4*)&S.W[i16 * FS + j0] = make_float4(r[0], r[1], r[2], r[3]);
  }
  WSYNC();
  mmv<false>(S.L4, S.F, S.W, i16, jg);         WSYNC();  // V6: PS = Phi @ sig_int

  {  // V7: out1 = Hom_var + PS @ Phi^T  (packed column-pair dot chains)
    float aA[16];
    load16(aA, &S.L4[i16 * FS]);
    float acc[4];
#pragma unroll
    for (int cp = 0; cp < 2; ++cp) {
      float bB0[16], bB1[16];
      load16(bB0, &S.F[(j0 + 2*cp) * FS]);
      load16(bB1, &S.F[(j0 + 2*cp + 1) * FS]);
      v2f s = {0.f, 0.f};
#pragma unroll
      for (int k = 0; k < 16; ++k)
        s = pkfma((v2f){aA[k], aA[k]}, (v2f){bB0[k], bB1[k]}, s);
      acc[2*cp] = s.x; acc[2*cp+1] = s.y;
    }
    float4 hv = *(const float4*)&S.L1[i16 * FS + j0];
    float4 o = make_float4(hv.x + acc[0], hv.y + acc[1], hv.z + acc[2], hv.w + acc[3]);
    *(float4*)&gOut1[(size_t)b * 256 + i16 * 16 + j0] = o;
  }
}

extern "C" void kernel_launch(void* const* d_in, const int* in_sizes, int n_in,
                              void* d_out, int out_size, void* d_ws, size_t ws_size,
                              hipStream_t stream) {
  const float* X0 = (const float*)d_in[0];
  const float* Xv = (const float*)d_in[1];
  const float* U  = (const float*)d_in[2];
  const float* T  = (const float*)d_in[3];
  const float* Q  = (const float*)d_in[4];
  const float* Lr = (const float*)d_in[5];
  const float* Li = (const float*)d_in[6];
  const float* Vr = (const float*)d_in[7];
  const float* Vi = (const float*)d_in[8];
  const int B = in_sizes[3];
  float* out0 = (float*)d_out;
  float* out1 = (float*)d_out + (size_t)B * 16;
  const int blocks = (B + 3) / 4;
  hipLaunchKernelGGL(nesde_kernel, dim3(blocks), dim3(256), 0, stream,
                     X0, Xv, U, T, Q, Lr, Li, Vr, Vi, out0, out1, B);
}